// Round 9
// baseline (305.390 us; speedup 1.0000x reference)
//
#include <hip/hip_runtime.h>
#include <hip/hip_bf16.h>
#include <hip/hip_fp16.h>
#include <cstddef>
#include <cstdint>

#define T_ 4
#define B_ 16
#define N_ 512
#define C_ 512
#define H_ 8
#define D_ 64
#define BN_T (B_*N_)   // 8192

typedef unsigned short u16;
typedef __attribute__((ext_vector_type(8))) short bf16x8;       // 8 bf16
typedef __attribute__((ext_vector_type(8))) _Float16 f16x8;     // 8 fp16
typedef __attribute__((ext_vector_type(8))) unsigned short u16x8;
typedef __attribute__((ext_vector_type(4))) float f32x4;

__device__ __forceinline__ u16 f2bf_exact(float f) {
    union { float f; unsigned u; } x; x.f = f; return (u16)(x.u >> 16);
}
// 2-term exact fp16 split: f == h1 + h2/2048 + tail(<=2^-22|f|)
__device__ __forceinline__ void split2(float f, u16& h1, u16& h2) {
    const __half a = __float2half(f);                   // RNE
    const float r = (f - __half2float(a)) * 2048.0f;    // exact (Sterbenz + pow2)
    const __half b = __float2half(r);
    h1 = __half_as_ushort(a); h2 = __half_as_ushort(b);
}
// XOR swizzle, 16B granularity, BYTE offset into a [128][32] fp16 tile (64B rows)
__device__ __forceinline__ int swz(int rr, int q) {
    return (rr << 6) + (((q ^ ((rr >> 1) & 3)) & 3) << 4);
}
// attention LDS swizzle (element index into [64][64] u16 tiles)
__device__ __forceinline__ int SW(int row, int col) {
    return (row << 6) + (col ^ ((row & 7) << 3));
}
// async global->LDS, 16B per lane (dest = uniform base + lane*16)
__device__ __forceinline__ void gload16(const void* g, void* l) {
    __builtin_amdgcn_global_load_lds(
        (const __attribute__((address_space(1))) unsigned int*)g,
        (__attribute__((address_space(3))) unsigned int*)l, 16, 0, 0);
}

// ---------------------------------------------------------------------------
// x fp32 [T,BN,C] -> tile-major pre-swizzled fp16 splits x1t, x2t.
// ---------------------------------------------------------------------------
__global__ __launch_bounds__(256) void k_split_x(
    const float* __restrict__ x, u16* __restrict__ x1t, u16* __restrict__ x2t)
{
    const int tile = blockIdx.x;            // mt*16 + kb  (4096 tiles)
    const int mt = tile >> 4, kb = tile & 15;
    const int tid = threadIdx.x;
    const int rr = tid >> 1, kh = tid & 1;
    const int t = rr & 3, bn = mt * 32 + (rr >> 2);
    const float* src = x + ((size_t)t * BN_T + bn) * C_ + kb * 32 + kh * 16;
    float f[16];
    *reinterpret_cast<float4*>(f + 0)  = *reinterpret_cast<const float4*>(src + 0);
    *reinterpret_cast<float4*>(f + 4)  = *reinterpret_cast<const float4*>(src + 4);
    *reinterpret_cast<float4*>(f + 8)  = *reinterpret_cast<const float4*>(src + 8);
    *reinterpret_cast<float4*>(f + 12) = *reinterpret_cast<const float4*>(src + 12);
    char* d1 = (char*)(x1t + ((size_t)tile << 12));
    char* d2 = (char*)(x2t + ((size_t)tile << 12));
    #pragma unroll
    for (int j = 0; j < 2; ++j) {
        u16x8 p1, p2;
        #pragma unroll
        for (int e = 0; e < 8; ++e) { u16 h1, h2; split2(f[8*j+e], h1, h2); p1[e] = h1; p2[e] = h2; }
        const int q = 2 * kh + j;
        *reinterpret_cast<u16x8*>(d1 + swz(rr, q)) = p1;
        *reinterpret_cast<u16x8*>(d2 + swz(rr, q)) = p2;
    }
}

// w fp32 [512][512] -> tile-major pre-swizzled fp16 splits
__global__ __launch_bounds__(256) void k_split_w(
    const float* __restrict__ w, u16* __restrict__ w1t, u16* __restrict__ w2t)
{
    const int tile = blockIdx.x;            // nt*16 + kb  (64 tiles)
    const int nt = tile >> 4, kb = tile & 15;
    const int tid = threadIdx.x;
    const int rr = tid >> 1, kh = tid & 1;
    const int c = nt * 128 + rr;
    const float* src = w + (size_t)c * C_ + kb * 32 + kh * 16;
    float f[16];
    *reinterpret_cast<float4*>(f + 0)  = *reinterpret_cast<const float4*>(src + 0);
    *reinterpret_cast<float4*>(f + 4)  = *reinterpret_cast<const float4*>(src + 4);
    *reinterpret_cast<float4*>(f + 8)  = *reinterpret_cast<const float4*>(src + 8);
    *reinterpret_cast<float4*>(f + 12) = *reinterpret_cast<const float4*>(src + 12);
    char* d1 = (char*)(w1t + ((size_t)tile << 12));
    char* d2 = (char*)(w2t + ((size_t)tile << 12));
    #pragma unroll
    for (int j = 0; j < 2; ++j) {
        u16x8 p1, p2;
        #pragma unroll
        for (int e = 0; e < 8; ++e) { u16 h1, h2; split2(f[8*j+e], h1, h2); p1[e] = h1; p2[e] = h2; }
        const int q = 2 * kh + j;
        *reinterpret_cast<u16x8*>(d1 + swz(rr, q)) = p1;
        *reinterpret_cast<u16x8*>(d2 + swz(rr, q)) = p2;
    }
}

// ---------------------------------------------------------------------------
// Merged Q/K/V split-fp16 MFMA Linear -> BN -> LIF(v_th=1) over T=4.
// A1/A2 fragments loaded DIRECTLY from global (pre-swizzled tiles; wave-
// private rows) with 1-step register prefetch in named even/odd buffers.
// Only B1/B2 staged in LDS (32KB dbuf). Waves 2x2, wave tile 64x64
// (rt=ct=4) so B-reads amortize over 4 rt. Numerics bit-identical.
// ---------------------------------------------------------------------------
__global__ __launch_bounds__(256, 2) void k_linear_qkv(
    const u16* __restrict__ a1t, const u16* __restrict__ a2t,
    const u16* __restrict__ wt_base,
    const float* __restrict__ bi0, const float* __restrict__ ga0, const float* __restrict__ be0,
    const float* __restrict__ mu0, const float* __restrict__ va0,
    const float* __restrict__ bi1, const float* __restrict__ ga1, const float* __restrict__ be1,
    const float* __restrict__ mu1, const float* __restrict__ va1,
    const float* __restrict__ bi2, const float* __restrict__ ga2, const float* __restrict__ be2,
    const float* __restrict__ mu2, const float* __restrict__ va2,
    u16* __restrict__ oq, u16* __restrict__ ok, u16* __restrict__ ov)
{
    __shared__ u16 lds[2][2][4096];   // [buf][B1,B2][8KB tile]  = 32KB

    const int dd  = blockIdx.x;                    // 0..3071
    const int lid = (dd & 7) * 384 + (dd >> 3);    // XCD swizzle (bijective)
    const int mt  = lid / 12;                      // 0..255
    const int ntg = lid - mt * 12;                 // 0..11
    const int li  = ntg >> 2;                      // which linear 0..2
    const int nt  = ntg & 3;
    const int bn0 = mt * 32;
    const int c0  = nt * 128;

    const float* bias  = li == 0 ? bi0 : li == 1 ? bi1 : bi2;
    const float* gamma = li == 0 ? ga0 : li == 1 ? ga1 : ga2;
    const float* beta  = li == 0 ? be0 : li == 1 ? be1 : be2;
    const float* mean  = li == 0 ? mu0 : li == 1 ? mu1 : mu2;
    const float* var   = li == 0 ? va0 : li == 1 ? va1 : va2;
    u16* outp = li == 0 ? oq : li == 1 ? ok : ov;

    const size_t WSZ = (size_t)C_ * C_;
    const u16* w1t = wt_base + (size_t)(2 * li) * WSZ;
    const u16* w2t = wt_base + (size_t)(2 * li + 1) * WSZ;

    const int tid = threadIdx.x;
    const int wv  = tid >> 6, lane = tid & 63;
    const int l15 = tid & 15, g = (tid & 63) >> 4;
    const int wr  = wv >> 1, wc = wv & 1;          // 2x2 wave grid
    const int go  = wv * 2048 + lane * 16;         // staging offset within array
    const int lo  = wv * 2048;

    f32x4 accA[4][4], accB[4][4];
    #pragma unroll
    for (int rt = 0; rt < 4; ++rt)
        #pragma unroll
        for (int ct = 0; ct < 4; ++ct) { accA[rt][ct] = {0,0,0,0}; accB[rt][ct] = {0,0,0,0}; }

    const size_t abase = (size_t)mt * 16, bbase = (size_t)nt * 16;

    auto stage = [&](int buf, int kb) {            // B1,B2 -> LDS (4 gloads/wave)
        char* L = (char*)&lds[buf][0][0];
        const char* gb1 = (const char*)(w1t + ((bbase + kb) << 12)) + go;
        const char* gb2 = (const char*)(w2t + ((bbase + kb) << 12)) + go;
        gload16(gb1,        L + lo);
        gload16(gb1 + 1024, L + lo + 1024);
        gload16(gb2,        L + 8192 + lo);
        gload16(gb2 + 1024, L + 8192 + lo + 1024);
    };
    auto lda = [&](int kb, f16x8 (&a1)[4], f16x8 (&a2)[4]) {   // A frags from global
        const char* t1 = (const char*)(a1t + ((abase + kb) << 12));
        const char* t2 = (const char*)(a2t + ((abase + kb) << 12));
        #pragma unroll
        for (int rt = 0; rt < 4; ++rt) {
            const int rr = 64 * wr + 16 * rt + l15;
            a1[rt] = *reinterpret_cast<const f16x8*>(t1 + swz(rr, g));
            a2[rt] = *reinterpret_cast<const f16x8*>(t2 + swz(rr, g));
        }
    };
    auto comp = [&](int buf, const f16x8 (&a1)[4], const f16x8 (&a2)[4]) {
        const char* L = (const char*)&lds[buf][0][0];
        #pragma unroll
        for (int ct = 0; ct < 4; ++ct) {
            const int rr2 = 64 * wc + 16 * ct + l15;
            const f16x8 b1 = *reinterpret_cast<const f16x8*>(L + swz(rr2, g));
            const f16x8 b2 = *reinterpret_cast<const f16x8*>(L + 8192 + swz(rr2, g));
            #pragma unroll
            for (int rt = 0; rt < 4; ++rt) {
                accA[rt][ct] = __builtin_amdgcn_mfma_f32_16x16x32_f16(a1[rt], b1, accA[rt][ct], 0, 0, 0);
                accB[rt][ct] = __builtin_amdgcn_mfma_f32_16x16x32_f16(a2[rt], b1, accB[rt][ct], 0, 0, 0);
                accB[rt][ct] = __builtin_amdgcn_mfma_f32_16x16x32_f16(a1[rt], b2, accB[rt][ct], 0, 0, 0);
            }
        }
    };

    f16x8 aE1[4], aE2[4], aO1[4], aO2[4];          // named even/odd prefetch bufs
    lda(0, aE1, aE2);
    stage(0, 0);
    __syncthreads();

    #pragma unroll 1
    for (int kb = 0; kb < 16; kb += 2) {
        lda(kb + 1, aO1, aO2);                     // kb+1 <= 15 always
        stage(1, kb + 1);
        comp(0, aE1, aE2);
        __syncthreads();                           // buf1 visible; buf0 free
        if (kb + 2 < 16) { lda(kb + 2, aE1, aE2); stage(0, kb + 2); }
        comp(1, aO1, aO2);
        __syncthreads();                           // buf0 visible; buf1 free
    }

    // epilogue: reconstruct -> bias -> BN -> LIF(v_th=1) over reg r==t
    #pragma unroll
    for (int ct = 0; ct < 4; ++ct) {
        const int c = c0 + 64 * wc + 16 * ct + l15;
        const float rs = 1.0f / sqrtf(var[c] + 1e-5f);
        const float ga = gamma[c], be = beta[c], mu = mean[c], bi = bias[c];
        #pragma unroll
        for (int rt = 0; rt < 4; ++rt) {
            const int bn = bn0 + 16 * wr + 4 * rt + g;
            float vm = 0.f;
            #pragma unroll
            for (int r = 0; r < 4; ++r) {
                const float y = accA[rt][ct][r] + accB[rt][ct][r] * (1.0f / 2048.0f) + bi;
                const float ybn = (y - mu) * rs * ga + be;
                const float h = vm + (ybn - vm) * 0.5f;
                const bool sp = (h >= 1.0f);
                vm = sp ? 0.f : h;
                const int b = bn >> 9, n = bn & 511;
                const int hh = c >> 6, d2 = c & 63;
                outp[((((size_t)r * B_ + b) * H_ + hh) * N_ + n) * D_ + d2] = sp ? 0x3F80 : 0;
            }
        }
    }
}

// ---------------------------------------------------------------------------
// Final split-fp16 MFMA Linear (spike fp16 input, 2 terms) -> BN -> LIF,
// fp32 0/1 out. Same A-global-direct / B-LDS structure as k_linear_qkv.
// ---------------------------------------------------------------------------
__global__ __launch_bounds__(256, 2) void k_linear_out(
    const u16* __restrict__ a1t,
    const u16* __restrict__ w1t, const u16* __restrict__ w2t,
    const float* __restrict__ bias, const float* __restrict__ gamma,
    const float* __restrict__ beta, const float* __restrict__ mean,
    const float* __restrict__ var, float* __restrict__ outp)
{
    __shared__ u16 lds[2][2][4096];   // [buf][B1,B2]

    const int dd  = blockIdx.x;
    const int lid = (dd & 7) * 128 + (dd >> 3);
    const int mt  = lid >> 2;
    const int nt  = lid & 3;
    const int bn0 = mt * 32;
    const int c0  = nt * 128;

    const int tid = threadIdx.x;
    const int wv  = tid >> 6, lane = tid & 63;
    const int l15 = tid & 15, g = (tid & 63) >> 4;
    const int wr  = wv >> 1, wc = wv & 1;
    const int go  = wv * 2048 + lane * 16;
    const int lo  = wv * 2048;

    f32x4 accA[4][4], accB[4][4];
    #pragma unroll
    for (int rt = 0; rt < 4; ++rt)
        #pragma unroll
        for (int ct = 0; ct < 4; ++ct) { accA[rt][ct] = {0,0,0,0}; accB[rt][ct] = {0,0,0,0}; }

    const size_t abase = (size_t)mt * 16, bbase = (size_t)nt * 16;

    auto stage = [&](int buf, int kb) {
        char* L = (char*)&lds[buf][0][0];
        const char* gb1 = (const char*)(w1t + ((bbase + kb) << 12)) + go;
        const char* gb2 = (const char*)(w2t + ((bbase + kb) << 12)) + go;
        gload16(gb1,        L + lo);
        gload16(gb1 + 1024, L + lo + 1024);
        gload16(gb2,        L + 8192 + lo);
        gload16(gb2 + 1024, L + 8192 + lo + 1024);
    };
    auto lda = [&](int kb, f16x8 (&a1)[4]) {
        const char* t1 = (const char*)(a1t + ((abase + kb) << 12));
        #pragma unroll
        for (int rt = 0; rt < 4; ++rt) {
            const int rr = 64 * wr + 16 * rt + l15;
            a1[rt] = *reinterpret_cast<const f16x8*>(t1 + swz(rr, g));
        }
    };
    auto comp = [&](int buf, const f16x8 (&a1)[4]) {
        const char* L = (const char*)&lds[buf][0][0];
        #pragma unroll
        for (int ct = 0; ct < 4; ++ct) {
            const int rr2 = 64 * wc + 16 * ct + l15;
            const f16x8 b1 = *reinterpret_cast<const f16x8*>(L + swz(rr2, g));
            const f16x8 b2 = *reinterpret_cast<const f16x8*>(L + 8192 + swz(rr2, g));
            #pragma unroll
            for (int rt = 0; rt < 4; ++rt) {
                accA[rt][ct] = __builtin_amdgcn_mfma_f32_16x16x32_f16(a1[rt], b1, accA[rt][ct], 0, 0, 0);
                accB[rt][ct] = __builtin_amdgcn_mfma_f32_16x16x32_f16(a1[rt], b2, accB[rt][ct], 0, 0, 0);
            }
        }
    };

    f16x8 aE1[4], aO1[4];
    lda(0, aE1);
    stage(0, 0);
    __syncthreads();

    #pragma unroll 1
    for (int kb = 0; kb < 16; kb += 2) {
        lda(kb + 1, aO1);
        stage(1, kb + 1);
        comp(0, aE1);
        __syncthreads();
        if (kb + 2 < 16) { lda(kb + 2, aE1); stage(0, kb + 2); }
        comp(1, aO1);
        __syncthreads();
    }

    #pragma unroll
    for (int ct = 0; ct < 4; ++ct) {
        const int c = c0 + 64 * wc + 16 * ct + l15;
        const float rs = 1.0f / sqrtf(var[c] + 1e-5f);
        const float ga = gamma[c], be = beta[c], mu = mean[c], bi = bias[c];
        #pragma unroll
        for (int rt = 0; rt < 4; ++rt) {
            const int bn = bn0 + 16 * wr + 4 * rt + g;
            float vm = 0.f;
            #pragma unroll
            for (int r = 0; r < 4; ++r) {
                const float y = accA[rt][ct][r] + accB[rt][ct][r] * (1.0f / 2048.0f) + bi;
                const float ybn = (y - mu) * rs * ga + be;
                const float h = vm + (ybn - vm) * 0.5f;
                const bool sp = (h >= 1.0f);
                vm = sp ? 0.f : h;
                outp[((size_t)r * BN_T + bn) * C_ + c] = sp ? 1.0f : 0.0f;
            }
        }
    }
}

// ---------------------------------------------------------------------------
// MFMA attention + LIF(0.5), whole-KV-in-LDS (verified round 8, unchanged).
// ---------------------------------------------------------------------------
__global__ __launch_bounds__(512, 2) void k_attn_mfma(
    const u16* __restrict__ qg, const u16* __restrict__ kg,
    const u16* __restrict__ vg, u16* __restrict__ s2t)
{
    __shared__ u16 kf[8][4096];    // full K  [jt][SW(kv,d)]   64KB
    __shared__ u16 vf[8][4096];    // full V^T [jt][SW(d,kv)]  64KB
    __shared__ u16 ssb[8][1024];   // per-wave S strip (16x64) 16KB

    const int id  = blockIdx.x;                 // 0..511
    const int lid = (id & 7) * 64 + (id >> 3);  // XCD swizzle; qt-siblings same XCD
    const int bh  = lid >> 2;                   // 0..127
    const int qt  = lid & 3;                    // 128-row q tile
    const int b   = bh >> 3, hh = bh & 7;

    const int tid  = threadIdx.x;
    const int w    = tid >> 6, lane = tid & 63;
    const int l15  = lane & 15, g = lane >> 4;

    const int vkv = (tid & 15) * 4;
    const int vd  = ((tid >> 4) & 15) * 4;

    bf16x8 qa[2];
    f32x4 vmem[4], oacc[4];
    #pragma unroll
    for (int d0 = 0; d0 < 4; ++d0) { vmem[d0] = {0,0,0,0}; oacc[d0] = {0,0,0,0}; }

    #pragma unroll 1
    for (int t = 0; t < T_; ++t) {
        const size_t base = ((size_t)t * (B_ * H_) + bh) * (size_t)(N_ * D_);
        if (t > 0) __syncthreads();            // readers of t-1 done

        {
            const size_t qrow = base + (size_t)(qt * 128 + 16 * w + l15) * D_;
            qa[0] = *reinterpret_cast<const bf16x8*>(qg + qrow + 8 * g);
            qa[1] = *reinterpret_cast<const bf16x8*>(qg + qrow + 32 + 8 * g);
        }
        {
            const u16* kb = kg + base;
            #pragma unroll
            for (int i = 0; i < 8; ++i) {
                const int r64 = tid >> 3;
                const int col = (tid & 7) * 8;
                const u16x8 v = *reinterpret_cast<const u16x8*>(kb + ((size_t)(tid + 512 * i)) * 8);
                *reinterpret_cast<u16x8*>(&kf[i][SW(r64, col)]) = v;
            }
        }
        {
            const u16* vb = vg + base;
            #pragma unroll
            for (int i = 0; i < 4; ++i) {
                const int jt = 2 * i + (tid >> 8);
                const int m0 = jt * 64;
                ushort4 r0 = *reinterpret_cast<const ushort4*>(vb + (size_t)(m0 + vkv + 0) * D_ + vd);
                ushort4 r1 = *reinterpret_cast<const ushort4*>(vb + (size_t)(m0 + vkv + 1) * D_ + vd);
                ushort4 r2 = *reinterpret_cast<const ushort4*>(vb + (size_t)(m0 + vkv + 2) * D_ + vd);
                ushort4 r3 = *reinterpret_cast<const ushort4*>(vb + (size_t)(m0 + vkv + 3) * D_ + vd);
                ushort4 wv4;
                wv4.x = r0.x; wv4.y = r1.x; wv4.z = r2.x; wv4.w = r3.x;
                *reinterpret_cast<ushort4*>(&vf[jt][SW(vd + 0, vkv)]) = wv4;
                wv4.x = r0.y; wv4.y = r1.y; wv4.z = r2.y; wv4.w = r3.y;
                *reinterpret_cast<ushort4*>(&vf[jt][SW(vd + 1, vkv)]) = wv4;
                wv4.x = r0.z; wv4.y = r1.z; wv4.z = r2.z; wv4.w = r3.z;
                *reinterpret_cast<ushort4*>(&vf[jt][SW(vd + 2, vkv)]) = wv4;
                wv4.x = r0.w; wv4.y = r1.w; wv4.z = r2.w; wv4.w = r3.w;
                *reinterpret_cast<ushort4*>(&vf[jt][SW(vd + 3, vkv)]) = wv4;
            }
        }
        __syncthreads();

        u16* sb = &ssb[w][0];
        #pragma unroll
        for (int jt = 0; jt < 8; ++jt) {
            __builtin_amdgcn_s_setprio(1);
            #pragma unroll
            for (int kvt = 0; kvt < 2; ++kvt) {
                f32x4 acc = {0.f, 0.f, 0.f, 0.f};
                #pragma unroll
                for (int c = 0; c < 2; ++c) {
                    const bf16x8 kb = *reinterpret_cast<const bf16x8*>(
                        &kf[jt][SW(16 * kvt + l15, 32 * c + 8 * g)]);
                    acc = __builtin_amdgcn_mfma_f32_16x16x32_bf16(qa[c], kb, acc, 0, 0, 0);
                }
                #pragma unroll
                for (int r = 0; r < 4; ++r)
                    sb[SW(4 * g + r, 16 * kvt + l15)] = f2bf_exact(acc[r]);
            }
            {
                const bf16x8 sa = *reinterpret_cast<const bf16x8*>(&sb[SW(l15, 8 * g)]);
                #pragma unroll
                for (int d0 = 0; d0 < 4; ++d0) {
                    const bf16x8 vb2 = *reinterpret_cast<const bf16x8*>(
                        &vf[jt][SW(16 * d0 + l15, 8 * g)]);
                    oacc[d0] = __builtin_amdgcn_mfma_f32_16x16x32_bf16(sa, vb2, oacc[d0], 0, 0, 0);
                }
            }
            #pragma unroll
            for (int kvt = 2; kvt < 4; ++kvt) {
                f32x4 acc = {0.f, 0.f, 0.f, 0.f};
                #pragma unroll
                for (int c = 0; c < 2; ++c) {
                    const bf16x8 kb = *reinterpret_cast<const bf16x8*>(
                        &kf[jt][SW(16 * kvt + l15, 32 * c + 8 * g)]);
                    acc = __builtin_amdgcn_mfma_f32_16x16x32_bf16(qa[c], kb, acc, 0, 0, 0);
                }
                #pragma unroll
                for (int r = 0; r < 4; ++r)
                    sb[SW(4 * g + r, 16 * kvt + l15)] = f2bf_exact(acc[r]);
            }
            {
                const bf16x8 sa = *reinterpret_cast<const bf16x8*>(&sb[SW(l15, 32 + 8 * g)]);
                #pragma unroll
                for (int d0 = 0; d0 < 4; ++d0) {
                    const bf16x8 vb2 = *reinterpret_cast<const bf16x8*>(
                        &vf[jt][SW(16 * d0 + l15, 32 + 8 * g)]);
                    oacc[d0] = __builtin_amdgcn_mfma_f32_16x16x32_bf16(sa, vb2, oacc[d0], 0, 0, 0);
                }
            }
            __builtin_amdgcn_s_setprio(0);
        }

        #pragma unroll
        for (int d0 = 0; d0 < 4; ++d0) {
            const int c = hh * 64 + d0 * 16 + l15;
            const int kb2 = c >> 5, kq = (c >> 3) & 3, e = c & 7;
            #pragma unroll
            for (int r = 0; r < 4; ++r) {
                const float o = oacc[d0][r] * 0.125f;
                const float h = vmem[d0][r] + (o - vmem[d0][r]) * 0.5f;
                const bool sp = (h >= 0.5f);
                vmem[d0][r] = sp ? 0.f : h;
                const int n = qt * 128 + 16 * w + 4 * g + r;
                const int bn = b * 512 + n;
                const int mt2 = bn >> 5;
                const int rr2 = (bn & 31) * 4 + t;
                const size_t off = (((size_t)mt2 * 16 + kb2) << 13) + (rr2 << 6)
                                 + (((kq ^ ((rr2 >> 1) & 3)) & 3) << 4) + (e << 1);
                *(u16*)((char*)s2t + off) = sp ? 0x3C00 : 0;   // fp16 1.0
            }
            oacc[d0] = {0.f, 0.f, 0.f, 0.f};
        }
    }
}

extern "C" void kernel_launch(void* const* d_in, const int* in_sizes, int n_in,
                              void* d_out, int out_size, void* d_ws, size_t ws_size,
                              hipStream_t stream)
{
    const float* x = (const float*)d_in[0];
    const float* W[4]  = {(const float*)d_in[1],  (const float*)d_in[7],  (const float*)d_in[13], (const float*)d_in[19]};
    const float* Bi[4] = {(const float*)d_in[2],  (const float*)d_in[8],  (const float*)d_in[14], (const float*)d_in[20]};
    const float* Ga[4] = {(const float*)d_in[3],  (const float*)d_in[9],  (const float*)d_in[15], (const float*)d_in[21]};
    const float* Be[4] = {(const float*)d_in[4],  (const float*)d_in[10], (const float*)d_in[16], (const float*)d_in[22]};
    const float* Mu[4] = {(const float*)d_in[5],  (const float*)d_in[11], (const float*)d_in[17], (const float*)d_in[23]};
    const float* Va[4] = {(const float*)d_in[6],  (const float*)d_in[12], (const float*)d_in[18], (const float*)d_in[24]};

    const size_t SPK = (size_t)T_ * B_ * N_ * C_;   // 16,777,216
    const size_t WSZ = (size_t)C_ * C_;             // 262,144
    u16* qb  = (u16*)d_ws;          // bf16 spikes [T,B,H,N,D]
    u16* kbf = qb + SPK;
    u16* vbf = kbf + SPK;
    u16* x1t = vbf + SPK;           // tiled x1; reused as s2t after linears
    u16* x2t = x1t + SPK;           // tiled x2
    u16* wt  = x2t + SPK;           // 4 weights x 2 splits x WSZ
    u16* s2t = x1t;                 // attn output overlays x1t (dead by then)

    dim3 blk(256);
    k_split_x<<<4096, blk, 0, stream>>>(x, x1t, x2t);
    for (int i = 0; i < 4; ++i)
        k_split_w<<<64, blk, 0, stream>>>(W[i], wt + (2*i) * WSZ, wt + (2*i+1) * WSZ);

    k_linear_qkv<<<3072, blk, 0, stream>>>(x1t, x2t, wt,
        Bi[0], Ga[0], Be[0], Mu[0], Va[0],
        Bi[1], Ga[1], Be[1], Mu[1], Va[1],
        Bi[2], Ga[2], Be[2], Mu[2], Va[2],
        qb, kbf, vbf);
    k_attn_mfma<<<512, dim3(512), 0, stream>>>(qb, kbf, vbf, s2t);
    k_linear_out<<<1024, blk, 0, stream>>>(s2t, wt + 6*WSZ, wt + 7*WSZ,
        Bi[3], Ga[3], Be[3], Mu[3], Va[3], (float*)d_out);
}

// Round 10
// 300.737 us; speedup vs baseline: 1.0155x; 1.0155x over previous
//
#include <hip/hip_runtime.h>
#include <hip/hip_bf16.h>
#include <hip/hip_fp16.h>
#include <cstddef>
#include <cstdint>

#define T_ 4
#define B_ 16
#define N_ 512
#define C_ 512
#define H_ 8
#define D_ 64
#define BN_T (B_*N_)   // 8192

typedef unsigned short u16;
typedef __attribute__((ext_vector_type(8))) short bf16x8;       // 8 bf16
typedef __attribute__((ext_vector_type(8))) _Float16 f16x8;     // 8 fp16
typedef __attribute__((ext_vector_type(8))) unsigned short u16x8;
typedef __attribute__((ext_vector_type(4))) float f32x4;

__device__ __forceinline__ u16 f2bf_exact(float f) {
    union { float f; unsigned u; } x; x.f = f; return (u16)(x.u >> 16);
}
// 2-term exact fp16 split: f == h1 + h2/2048 + tail(<=2^-22|f|)
__device__ __forceinline__ void split2(float f, u16& h1, u16& h2) {
    const __half a = __float2half(f);                   // RNE
    const float r = (f - __half2float(a)) * 2048.0f;    // exact (Sterbenz + pow2)
    const __half b = __float2half(r);
    h1 = __half_as_ushort(a); h2 = __half_as_ushort(b);
}
// XOR swizzle, 16B granularity, BYTE offset into a [128][32] fp16 tile (64B rows)
__device__ __forceinline__ int swz(int rr, int q) {
    return (rr << 6) + (((q ^ ((rr >> 1) & 3)) & 3) << 4);
}
// attention LDS swizzle (element index into [64][64] u16 tiles)
__device__ __forceinline__ int SW(int row, int col) {
    return (row << 6) + (col ^ ((row & 7) << 3));
}
// async global->LDS, 16B per lane (dest = uniform base + lane*16)
__device__ __forceinline__ void gload16(const void* g, void* l) {
    __builtin_amdgcn_global_load_lds(
        (const __attribute__((address_space(1))) unsigned int*)g,
        (__attribute__((address_space(3))) unsigned int*)l, 16, 0, 0);
}

// ---------------------------------------------------------------------------
// x fp32 [T,BN,C] -> tile-major pre-swizzled fp16 splits x1t, x2t.
// ---------------------------------------------------------------------------
__global__ __launch_bounds__(256) void k_split_x(
    const float* __restrict__ x, u16* __restrict__ x1t, u16* __restrict__ x2t)
{
    const int tile = blockIdx.x;            // mt*16 + kb  (4096 tiles)
    const int mt = tile >> 4, kb = tile & 15;
    const int tid = threadIdx.x;
    const int rr = tid >> 1, kh = tid & 1;
    const int t = rr & 3, bn = mt * 32 + (rr >> 2);
    const float* src = x + ((size_t)t * BN_T + bn) * C_ + kb * 32 + kh * 16;
    float f[16];
    *reinterpret_cast<float4*>(f + 0)  = *reinterpret_cast<const float4*>(src + 0);
    *reinterpret_cast<float4*>(f + 4)  = *reinterpret_cast<const float4*>(src + 4);
    *reinterpret_cast<float4*>(f + 8)  = *reinterpret_cast<const float4*>(src + 8);
    *reinterpret_cast<float4*>(f + 12) = *reinterpret_cast<const float4*>(src + 12);
    char* d1 = (char*)(x1t + ((size_t)tile << 12));
    char* d2 = (char*)(x2t + ((size_t)tile << 12));
    #pragma unroll
    for (int j = 0; j < 2; ++j) {
        u16x8 p1, p2;
        #pragma unroll
        for (int e = 0; e < 8; ++e) { u16 h1, h2; split2(f[8*j+e], h1, h2); p1[e] = h1; p2[e] = h2; }
        const int q = 2 * kh + j;
        *reinterpret_cast<u16x8*>(d1 + swz(rr, q)) = p1;
        *reinterpret_cast<u16x8*>(d2 + swz(rr, q)) = p2;
    }
}

// w fp32 [512][512] -> tile-major pre-swizzled fp16 splits
__global__ __launch_bounds__(256) void k_split_w(
    const float* __restrict__ w, u16* __restrict__ w1t, u16* __restrict__ w2t)
{
    const int tile = blockIdx.x;            // nt*16 + kb  (64 tiles)
    const int nt = tile >> 4, kb = tile & 15;
    const int tid = threadIdx.x;
    const int rr = tid >> 1, kh = tid & 1;
    const int c = nt * 128 + rr;
    const float* src = w + (size_t)c * C_ + kb * 32 + kh * 16;
    float f[16];
    *reinterpret_cast<float4*>(f + 0)  = *reinterpret_cast<const float4*>(src + 0);
    *reinterpret_cast<float4*>(f + 4)  = *reinterpret_cast<const float4*>(src + 4);
    *reinterpret_cast<float4*>(f + 8)  = *reinterpret_cast<const float4*>(src + 8);
    *reinterpret_cast<float4*>(f + 12) = *reinterpret_cast<const float4*>(src + 12);
    char* d1 = (char*)(w1t + ((size_t)tile << 12));
    char* d2 = (char*)(w2t + ((size_t)tile << 12));
    #pragma unroll
    for (int j = 0; j < 2; ++j) {
        u16x8 p1, p2;
        #pragma unroll
        for (int e = 0; e < 8; ++e) { u16 h1, h2; split2(f[8*j+e], h1, h2); p1[e] = h1; p2[e] = h2; }
        const int q = 2 * kh + j;
        *reinterpret_cast<u16x8*>(d1 + swz(rr, q)) = p1;
        *reinterpret_cast<u16x8*>(d2 + swz(rr, q)) = p2;
    }
}

// ---------------------------------------------------------------------------
// Merged Q/K/V split-fp16 MFMA Linear -> BN -> LIF(v_th=1) over T=4.
// T4 structure: 512 thr (2x4 waves, wave tile 64x64), block tile 128x256,
// BK=32, THREE LDS buffers (48KB each) with counted vmcnt(6): stage(k+2)
// issued at iter k, loads stay in flight across the barrier; only lgkm is
// drained. Numerics bit-identical to the verified split-fp16 scheme.
// ---------------------------------------------------------------------------
__global__ __launch_bounds__(512, 2) void k_linear_qkv(
    const u16* __restrict__ a1t, const u16* __restrict__ a2t,
    const u16* __restrict__ wt_base,
    const float* __restrict__ bi0, const float* __restrict__ ga0, const float* __restrict__ be0,
    const float* __restrict__ mu0, const float* __restrict__ va0,
    const float* __restrict__ bi1, const float* __restrict__ ga1, const float* __restrict__ be1,
    const float* __restrict__ mu1, const float* __restrict__ va1,
    const float* __restrict__ bi2, const float* __restrict__ ga2, const float* __restrict__ be2,
    const float* __restrict__ mu2, const float* __restrict__ va2,
    u16* __restrict__ oq, u16* __restrict__ ok, u16* __restrict__ ov)
{
    // [buf][unit][8KB]; units: A1,A2,B1a,B1b,B2a,B2b  -> 3 x 48KB = 144KB
    __shared__ u16 lds[3][6][4096];

    const int dd  = blockIdx.x;                    // 0..1535
    const int lid = (dd & 7) * 192 + (dd >> 3);    // XCD swizzle (bijective)
    const int mt  = lid / 6;                       // 0..255
    const int rem = lid - mt * 6;
    const int li  = rem >> 1;                      // which linear 0..2
    const int nt  = rem & 1;                       // 256-col tile
    const int bn0 = mt * 32;
    const int c0  = nt * 256;

    const float* bias  = li == 0 ? bi0 : li == 1 ? bi1 : bi2;
    const float* gamma = li == 0 ? ga0 : li == 1 ? ga1 : ga2;
    const float* beta  = li == 0 ? be0 : li == 1 ? be1 : be2;
    const float* mean  = li == 0 ? mu0 : li == 1 ? mu1 : mu2;
    const float* var   = li == 0 ? va0 : li == 1 ? va1 : va2;
    u16* outp = li == 0 ? oq : li == 1 ? ok : ov;

    const size_t WSZ = (size_t)C_ * C_;
    const u16* w1t = wt_base + (size_t)(2 * li) * WSZ;
    const u16* w2t = wt_base + (size_t)(2 * li + 1) * WSZ;

    const int tid = threadIdx.x;
    const int wv  = tid >> 6, lane = tid & 63;
    const int l15 = lane & 15, g = (lane >> 4) & 3;
    const int wr  = wv >> 2, wc = wv & 3;          // 2x4 wave grid
    const int so  = tid * 16;                      // byte offset in 8KB unit

    f32x4 accA[4][4], accB[4][4];
    #pragma unroll
    for (int rt = 0; rt < 4; ++rt)
        #pragma unroll
        for (int ct = 0; ct < 4; ++ct) { accA[rt][ct] = {0,0,0,0}; accB[rt][ct] = {0,0,0,0}; }

    const size_t abase  = (size_t)mt * 16;
    const size_t bbase0 = (size_t)(nt * 2 + 0) * 16;
    const size_t bbase1 = (size_t)(nt * 2 + 1) * 16;

    auto stage = [&](int buf, int kb) {            // 6 gload16 / thread
        char* L = (char*)&lds[buf][0][0];
        gload16((const char*)(a1t + ((abase  + kb) << 12)) + so, L + 0 * 8192 + so);
        gload16((const char*)(a2t + ((abase  + kb) << 12)) + so, L + 1 * 8192 + so);
        gload16((const char*)(w1t + ((bbase0 + kb) << 12)) + so, L + 2 * 8192 + so);
        gload16((const char*)(w1t + ((bbase1 + kb) << 12)) + so, L + 3 * 8192 + so);
        gload16((const char*)(w2t + ((bbase0 + kb) << 12)) + so, L + 4 * 8192 + so);
        gload16((const char*)(w2t + ((bbase1 + kb) << 12)) + so, L + 5 * 8192 + so);
    };
    auto comp = [&](int buf) {
        const char* L = (const char*)&lds[buf][0][0];
        f16x8 a1[4], a2[4];
        #pragma unroll
        for (int rt = 0; rt < 4; ++rt) {
            const int rr = 64 * wr + 16 * rt + l15;
            a1[rt] = *reinterpret_cast<const f16x8*>(L + 0 * 8192 + swz(rr, g));
            a2[rt] = *reinterpret_cast<const f16x8*>(L + 1 * 8192 + swz(rr, g));
        }
        __builtin_amdgcn_s_setprio(1);
        #pragma unroll
        for (int ct = 0; ct < 4; ++ct) {
            const int cc = 64 * wc + 16 * ct;       // col base within 256
            const int ub = 2 + (cc >> 7);           // B1 unit (2 or 3)
            const int rrB = (cc & 127) + l15;
            const f16x8 b1 = *reinterpret_cast<const f16x8*>(L + ub * 8192 + swz(rrB, g));
            const f16x8 b2 = *reinterpret_cast<const f16x8*>(L + (ub + 2) * 8192 + swz(rrB, g));
            #pragma unroll
            for (int rt = 0; rt < 4; ++rt) {
                accA[rt][ct] = __builtin_amdgcn_mfma_f32_16x16x32_f16(a1[rt], b1, accA[rt][ct], 0, 0, 0);
                accB[rt][ct] = __builtin_amdgcn_mfma_f32_16x16x32_f16(a2[rt], b1, accB[rt][ct], 0, 0, 0);
                accB[rt][ct] = __builtin_amdgcn_mfma_f32_16x16x32_f16(a1[rt], b2, accB[rt][ct], 0, 0, 0);
            }
        }
        __builtin_amdgcn_s_setprio(0);
    };

    // prologue: tiles 0,1 staged; wait only for tile 0 (6 newest stay in flight)
    stage(0, 0);
    stage(1, 1);
    __builtin_amdgcn_sched_barrier(0);
    asm volatile("s_waitcnt vmcnt(6) lgkmcnt(0)" ::: "memory");
    __builtin_amdgcn_s_barrier();
    __builtin_amdgcn_sched_barrier(0);

    #pragma unroll 1
    for (int k = 0; k < 14; ++k) {
        stage((k + 2) % 3, k + 2);                 // in flight across barrier
        comp(k % 3);
        __builtin_amdgcn_sched_barrier(0);
        asm volatile("s_waitcnt vmcnt(6) lgkmcnt(0)" ::: "memory");
        __builtin_amdgcn_s_barrier();
        __builtin_amdgcn_sched_barrier(0);
    }
    // k = 14: nothing left to stage; drain tile-15 loads fully
    comp(14 % 3);
    __builtin_amdgcn_sched_barrier(0);
    asm volatile("s_waitcnt vmcnt(0) lgkmcnt(0)" ::: "memory");
    __builtin_amdgcn_s_barrier();
    __builtin_amdgcn_sched_barrier(0);
    // k = 15
    comp(15 % 3);

    // epilogue: reconstruct -> bias -> BN -> LIF(v_th=1) over reg r==t
    #pragma unroll
    for (int ct = 0; ct < 4; ++ct) {
        const int c = c0 + 64 * wc + 16 * ct + l15;
        const float rs = 1.0f / sqrtf(var[c] + 1e-5f);
        const float ga = gamma[c], be = beta[c], mu = mean[c], bi = bias[c];
        #pragma unroll
        for (int rt = 0; rt < 4; ++rt) {
            const int bn = bn0 + 16 * wr + 4 * rt + g;
            float vm = 0.f;
            #pragma unroll
            for (int r = 0; r < 4; ++r) {
                const float y = accA[rt][ct][r] + accB[rt][ct][r] * (1.0f / 2048.0f) + bi;
                const float ybn = (y - mu) * rs * ga + be;
                const float h = vm + (ybn - vm) * 0.5f;
                const bool sp = (h >= 1.0f);
                vm = sp ? 0.f : h;
                const int b = bn >> 9, n = bn & 511;
                const int hh = c >> 6, d2 = c & 63;
                outp[((((size_t)r * B_ + b) * H_ + hh) * N_ + n) * D_ + d2] = sp ? 0x3F80 : 0;
            }
        }
    }
}

// ---------------------------------------------------------------------------
// Final split-fp16 MFMA Linear (spike fp16 input, 2 terms) -> BN -> LIF,
// fp32 0/1 out. Same T4 counted-vmcnt structure; units A1,B1a,B1b,B2a,B2b.
// ---------------------------------------------------------------------------
__global__ __launch_bounds__(512, 2) void k_linear_out(
    const u16* __restrict__ a1t,
    const u16* __restrict__ w1t, const u16* __restrict__ w2t,
    const float* __restrict__ bias, const float* __restrict__ gamma,
    const float* __restrict__ beta, const float* __restrict__ mean,
    const float* __restrict__ var, float* __restrict__ outp)
{
    __shared__ u16 lds[3][5][4096];   // 3 x 40KB = 120KB

    const int dd  = blockIdx.x;                   // 0..511
    const int lid = (dd & 7) * 64 + (dd >> 3);
    const int mt  = lid >> 1;                     // 0..255
    const int nt  = lid & 1;
    const int bn0 = mt * 32;
    const int c0  = nt * 256;

    const int tid = threadIdx.x;
    const int wv  = tid >> 6, lane = tid & 63;
    const int l15 = lane & 15, g = (lane >> 4) & 3;
    const int wr  = wv >> 2, wc = wv & 3;
    const int so  = tid * 16;

    f32x4 accA[4][4], accB[4][4];
    #pragma unroll
    for (int rt = 0; rt < 4; ++rt)
        #pragma unroll
        for (int ct = 0; ct < 4; ++ct) { accA[rt][ct] = {0,0,0,0}; accB[rt][ct] = {0,0,0,0}; }

    const size_t abase  = (size_t)mt * 16;
    const size_t bbase0 = (size_t)(nt * 2 + 0) * 16;
    const size_t bbase1 = (size_t)(nt * 2 + 1) * 16;

    auto stage = [&](int buf, int kb) {           // 5 gload16 / thread
        char* L = (char*)&lds[buf][0][0];
        gload16((const char*)(a1t + ((abase  + kb) << 12)) + so, L + 0 * 8192 + so);
        gload16((const char*)(w1t + ((bbase0 + kb) << 12)) + so, L + 1 * 8192 + so);
        gload16((const char*)(w1t + ((bbase1 + kb) << 12)) + so, L + 2 * 8192 + so);
        gload16((const char*)(w2t + ((bbase0 + kb) << 12)) + so, L + 3 * 8192 + so);
        gload16((const char*)(w2t + ((bbase1 + kb) << 12)) + so, L + 4 * 8192 + so);
    };
    auto comp = [&](int buf) {
        const char* L = (const char*)&lds[buf][0][0];
        f16x8 a1[4];
        #pragma unroll
        for (int rt = 0; rt < 4; ++rt) {
            const int rr = 64 * wr + 16 * rt + l15;
            a1[rt] = *reinterpret_cast<const f16x8*>(L + 0 * 8192 + swz(rr, g));
        }
        __builtin_amdgcn_s_setprio(1);
        #pragma unroll
        for (int ct = 0; ct < 4; ++ct) {
            const int cc = 64 * wc + 16 * ct;
            const int ub = 1 + (cc >> 7);          // B1 unit (1 or 2)
            const int rrB = (cc & 127) + l15;
            const f16x8 b1 = *reinterpret_cast<const f16x8*>(L + ub * 8192 + swz(rrB, g));
            const f16x8 b2 = *reinterpret_cast<const f16x8*>(L + (ub + 2) * 8192 + swz(rrB, g));
            #pragma unroll
            for (int rt = 0; rt < 4; ++rt) {
                accA[rt][ct] = __builtin_amdgcn_mfma_f32_16x16x32_f16(a1[rt], b1, accA[rt][ct], 0, 0, 0);
                accB[rt][ct] = __builtin_amdgcn_mfma_f32_16x16x32_f16(a1[rt], b2, accB[rt][ct], 0, 0, 0);
            }
        }
        __builtin_amdgcn_s_setprio(0);
    };

    stage(0, 0);
    stage(1, 1);
    __builtin_amdgcn_sched_barrier(0);
    asm volatile("s_waitcnt vmcnt(5) lgkmcnt(0)" ::: "memory");
    __builtin_amdgcn_s_barrier();
    __builtin_amdgcn_sched_barrier(0);

    #pragma unroll 1
    for (int k = 0; k < 14; ++k) {
        stage((k + 2) % 3, k + 2);
        comp(k % 3);
        __builtin_amdgcn_sched_barrier(0);
        asm volatile("s_waitcnt vmcnt(5) lgkmcnt(0)" ::: "memory");
        __builtin_amdgcn_s_barrier();
        __builtin_amdgcn_sched_barrier(0);
    }
    comp(14 % 3);
    __builtin_amdgcn_sched_barrier(0);
    asm volatile("s_waitcnt vmcnt(0) lgkmcnt(0)" ::: "memory");
    __builtin_amdgcn_s_barrier();
    __builtin_amdgcn_sched_barrier(0);
    comp(15 % 3);

    #pragma unroll
    for (int ct = 0; ct < 4; ++ct) {
        const int c = c0 + 64 * wc + 16 * ct + l15;
        const float rs = 1.0f / sqrtf(var[c] + 1e-5f);
        const float ga = gamma[c], be = beta[c], mu = mean[c], bi = bias[c];
        #pragma unroll
        for (int rt = 0; rt < 4; ++rt) {
            const int bn = bn0 + 16 * wr + 4 * rt + g;
            float vm = 0.f;
            #pragma unroll
            for (int r = 0; r < 4; ++r) {
                const float y = accA[rt][ct][r] + accB[rt][ct][r] * (1.0f / 2048.0f) + bi;
                const float ybn = (y - mu) * rs * ga + be;
                const float h = vm + (ybn - vm) * 0.5f;
                const bool sp = (h >= 1.0f);
                vm = sp ? 0.f : h;
                outp[((size_t)r * BN_T + bn) * C_ + c] = sp ? 1.0f : 0.0f;
            }
        }
    }
}

// ---------------------------------------------------------------------------
// MFMA attention + LIF(0.5), whole-KV-in-LDS (verified round 8, unchanged).
// ---------------------------------------------------------------------------
__global__ __launch_bounds__(512, 2) void k_attn_mfma(
    const u16* __restrict__ qg, const u16* __restrict__ kg,
    const u16* __restrict__ vg, u16* __restrict__ s2t)
{
    __shared__ u16 kf[8][4096];    // full K  [jt][SW(kv,d)]   64KB
    __shared__ u16 vf[8][4096];    // full V^T [jt][SW(d,kv)]  64KB
    __shared__ u16 ssb[8][1024];   // per-wave S strip (16x64) 16KB

    const int id  = blockIdx.x;                 // 0..511
    const int lid = (id & 7) * 64 + (id >> 3);  // XCD swizzle; qt-siblings same XCD
    const int bh  = lid >> 2;                   // 0..127
    const int qt  = lid & 3;                    // 128-row q tile
    const int b   = bh >> 3, hh = bh & 7;

    const int tid  = threadIdx.x;
    const int w    = tid >> 6, lane = tid & 63;
    const int l15  = lane & 15, g = lane >> 4;

    const int vkv = (tid & 15) * 4;
    const int vd  = ((tid >> 4) & 15) * 4;

    bf16x8 qa[2];
    f32x4 vmem[4], oacc[4];
    #pragma unroll
    for (int d0 = 0; d0 < 4; ++d0) { vmem[d0] = {0,0,0,0}; oacc[d0] = {0,0,0,0}; }

    #pragma unroll 1
    for (int t = 0; t < T_; ++t) {
        const size_t base = ((size_t)t * (B_ * H_) + bh) * (size_t)(N_ * D_);
        if (t > 0) __syncthreads();            // readers of t-1 done

        {
            const size_t qrow = base + (size_t)(qt * 128 + 16 * w + l15) * D_;
            qa[0] = *reinterpret_cast<const bf16x8*>(qg + qrow + 8 * g);
            qa[1] = *reinterpret_cast<const bf16x8*>(qg + qrow + 32 + 8 * g);
        }
        {
            const u16* kb = kg + base;
            #pragma unroll
            for (int i = 0; i < 8; ++i) {
                const int r64 = tid >> 3;
                const int col = (tid & 7) * 8;
                const u16x8 v = *reinterpret_cast<const u16x8*>(kb + ((size_t)(tid + 512 * i)) * 8);
                *reinterpret_cast<u16x8*>(&kf[i][SW(r64, col)]) = v;
            }
        }
        {
            const u16* vb = vg + base;
            #pragma unroll
            for (int i = 0; i < 4; ++i) {
                const int jt = 2 * i + (tid >> 8);
                const int m0 = jt * 64;
                ushort4 r0 = *reinterpret_cast<const ushort4*>(vb + (size_t)(m0 + vkv + 0) * D_ + vd);
                ushort4 r1 = *reinterpret_cast<const ushort4*>(vb + (size_t)(m0 + vkv + 1) * D_ + vd);
                ushort4 r2 = *reinterpret_cast<const ushort4*>(vb + (size_t)(m0 + vkv + 2) * D_ + vd);
                ushort4 r3 = *reinterpret_cast<const ushort4*>(vb + (size_t)(m0 + vkv + 3) * D_ + vd);
                ushort4 wv4;
                wv4.x = r0.x; wv4.y = r1.x; wv4.z = r2.x; wv4.w = r3.x;
                *reinterpret_cast<ushort4*>(&vf[jt][SW(vd + 0, vkv)]) = wv4;
                wv4.x = r0.y; wv4.y = r1.y; wv4.z = r2.y; wv4.w = r3.y;
                *reinterpret_cast<ushort4*>(&vf[jt][SW(vd + 1, vkv)]) = wv4;
                wv4.x = r0.z; wv4.y = r1.z; wv4.z = r2.z; wv4.w = r3.z;
                *reinterpret_cast<ushort4*>(&vf[jt][SW(vd + 2, vkv)]) = wv4;
                wv4.x = r0.w; wv4.y = r1.w; wv4.z = r2.w; wv4.w = r3.w;
                *reinterpret_cast<ushort4*>(&vf[jt][SW(vd + 3, vkv)]) = wv4;
            }
        }
        __syncthreads();

        u16* sb = &ssb[w][0];
        #pragma unroll
        for (int jt = 0; jt < 8; ++jt) {
            __builtin_amdgcn_s_setprio(1);
            #pragma unroll
            for (int kvt = 0; kvt < 2; ++kvt) {
                f32x4 acc = {0.f, 0.f, 0.f, 0.f};
                #pragma unroll
                for (int c = 0; c < 2; ++c) {
                    const bf16x8 kb = *reinterpret_cast<const bf16x8*>(
                        &kf[jt][SW(16 * kvt + l15, 32 * c + 8 * g)]);
                    acc = __builtin_amdgcn_mfma_f32_16x16x32_bf16(qa[c], kb, acc, 0, 0, 0);
                }
                #pragma unroll
                for (int r = 0; r < 4; ++r)
                    sb[SW(4 * g + r, 16 * kvt + l15)] = f2bf_exact(acc[r]);
            }
            {
                const bf16x8 sa = *reinterpret_cast<const bf16x8*>(&sb[SW(l15, 8 * g)]);
                #pragma unroll
                for (int d0 = 0; d0 < 4; ++d0) {
                    const bf16x8 vb2 = *reinterpret_cast<const bf16x8*>(
                        &vf[jt][SW(16 * d0 + l15, 8 * g)]);
                    oacc[d0] = __builtin_amdgcn_mfma_f32_16x16x32_bf16(sa, vb2, oacc[d0], 0, 0, 0);
                }
            }
            #pragma unroll
            for (int kvt = 2; kvt < 4; ++kvt) {
                f32x4 acc = {0.f, 0.f, 0.f, 0.f};
                #pragma unroll
                for (int c = 0; c < 2; ++c) {
                    const bf16x8 kb = *reinterpret_cast<const bf16x8*>(
                        &kf[jt][SW(16 * kvt + l15, 32 * c + 8 * g)]);
                    acc = __builtin_amdgcn_mfma_f32_16x16x32_bf16(qa[c], kb, acc, 0, 0, 0);
                }
                #pragma unroll
                for (int r = 0; r < 4; ++r)
                    sb[SW(4 * g + r, 16 * kvt + l15)] = f2bf_exact(acc[r]);
            }
            {
                const bf16x8 sa = *reinterpret_cast<const bf16x8*>(&sb[SW(l15, 32 + 8 * g)]);
                #pragma unroll
                for (int d0 = 0; d0 < 4; ++d0) {
                    const bf16x8 vb2 = *reinterpret_cast<const bf16x8*>(
                        &vf[jt][SW(16 * d0 + l15, 32 + 8 * g)]);
                    oacc[d0] = __builtin_amdgcn_mfma_f32_16x16x32_bf16(sa, vb2, oacc[d0], 0, 0, 0);
                }
            }
            __builtin_amdgcn_s_setprio(0);
        }

        #pragma unroll
        for (int d0 = 0; d0 < 4; ++d0) {
            const int c = hh * 64 + d0 * 16 + l15;
            const int kb2 = c >> 5, kq = (c >> 3) & 3, e = c & 7;
            #pragma unroll
            for (int r = 0; r < 4; ++r) {
                const float o = oacc[d0][r] * 0.125f;
                const float h = vmem[d0][r] + (o - vmem[d0][r]) * 0.5f;
                const bool sp = (h >= 0.5f);
                vmem[d0][r] = sp ? 0.f : h;
                const int n = qt * 128 + 16 * w + 4 * g + r;
                const int bn = b * 512 + n;
                const int mt2 = bn >> 5;
                const int rr2 = (bn & 31) * 4 + t;
                const size_t off = (((size_t)mt2 * 16 + kb2) << 13) + (rr2 << 6)
                                 + (((kq ^ ((rr2 >> 1) & 3)) & 3) << 4) + (e << 1);
                *(u16*)((char*)s2t + off) = sp ? 0x3C00 : 0;   // fp16 1.0
            }
            oacc[d0] = {0.f, 0.f, 0.f, 0.f};
        }
    }
}

extern "C" void kernel_launch(void* const* d_in, const int* in_sizes, int n_in,
                              void* d_out, int out_size, void* d_ws, size_t ws_size,
                              hipStream_t stream)
{
    const float* x = (const float*)d_in[0];
    const float* W[4]  = {(const float*)d_in[1],  (const float*)d_in[7],  (const float*)d_in[13], (const float*)d_in[19]};
    const float* Bi[4] = {(const float*)d_in[2],  (const float*)d_in[8],  (const float*)d_in[14], (const float*)d_in[20]};
    const float* Ga[4] = {(const float*)d_in[3],  (const float*)d_in[9],  (const float*)d_in[15], (const float*)d_in[21]};
    const float* Be[4] = {(const float*)d_in[4],  (const float*)d_in[10], (const float*)d_in[16], (const float*)d_in[22]};
    const float* Mu[4] = {(const float*)d_in[5],  (const float*)d_in[11], (const float*)d_in[17], (const float*)d_in[23]};
    const float* Va[4] = {(const float*)d_in[6],  (const float*)d_in[12], (const float*)d_in[18], (const float*)d_in[24]};

    const size_t SPK = (size_t)T_ * B_ * N_ * C_;   // 16,777,216
    const size_t WSZ = (size_t)C_ * C_;             // 262,144
    u16* qb  = (u16*)d_ws;          // bf16 spikes [T,B,H,N,D]
    u16* kbf = qb + SPK;
    u16* vbf = kbf + SPK;
    u16* x1t = vbf + SPK;           // tiled x1; reused as s2t after linears
    u16* x2t = x1t + SPK;           // tiled x2
    u16* wt  = x2t + SPK;           // 4 weights x 2 splits x WSZ
    u16* s2t = x1t;                 // attn output overlays x1t (dead by then)

    dim3 blk(256);
    k_split_x<<<4096, blk, 0, stream>>>(x, x1t, x2t);
    for (int i = 0; i < 4; ++i)
        k_split_w<<<64, blk, 0, stream>>>(W[i], wt + (2*i) * WSZ, wt + (2*i+1) * WSZ);

    k_linear_qkv<<<1536, dim3(512), 0, stream>>>(x1t, x2t, wt,
        Bi[0], Ga[0], Be[0], Mu[0], Va[0],
        Bi[1], Ga[1], Be[1], Mu[1], Va[1],
        Bi[2], Ga[2], Be[2], Mu[2], Va[2],
        qb, kbf, vbf);
    k_attn_mfma<<<512, dim3(512), 0, stream>>>(qb, kbf, vbf, s2t);
    k_linear_out<<<512, dim3(512), 0, stream>>>(s2t, wt + 6*WSZ, wt + 7*WSZ,
        Bi[3], Ga[3], Be[3], Mu[3], Va[3], (float*)d_out);
}